// Round 1
// baseline (391.145 us; speedup 1.0000x reference)
//
#include <hip/hip_runtime.h>
#include <math.h>

#define NND 4096
#define SDIM 128
#define HEADS 4
#define D1 64
#define HID 256
#define D2 256
#define C2 1024
#define NP1 (NND + 1)
#define CH 16
#define CHROWS 256
#define LEAKY 0.2f
#define LN_EPS 1e-5f

__device__ __forceinline__ float wave_sum(float v) {
#pragma unroll
    for (int o = 32; o > 0; o >>= 1) v += __shfl_xor(v, o, 64);
    return v;
}

__device__ __forceinline__ int lower_bound_f(const float* __restrict__ a, float x) {
    int lo = 0, hi = NND;
    while (lo < hi) {
        int mid = (lo + hi) >> 1;
        if (a[mid] < x) lo = mid + 1; else hi = mid;
    }
    return lo;
}

// ---------------- GEMM1: Wx1 = x (4096x128) @ W1 (128x256) ----------------
__global__ void gemm1_k(const float* __restrict__ x, const float* __restrict__ W1,
                        float* __restrict__ Wx1) {
    __shared__ float xs[8 * SDIM];
    const int i0 = blockIdx.x * 8;
    const int t = threadIdx.x;
    for (int p = t; p < 8 * SDIM; p += 256) xs[p] = x[i0 * SDIM + p];
    __syncthreads();
    float acc[8] = {0.f, 0.f, 0.f, 0.f, 0.f, 0.f, 0.f, 0.f};
    for (int k = 0; k < SDIM; k++) {
        float wv = W1[k * HID + t];
#pragma unroll
        for (int r = 0; r < 8; r++) acc[r] += xs[r * SDIM + k] * wv;
    }
#pragma unroll
    for (int r = 0; r < 8; r++) Wx1[(i0 + r) * HID + t] = acc[r];
}

// ---------------- GEMM2: Wx2 = h1 (4096x256) @ W2 (256x1024) ----------------
__global__ void gemm2_k(const float* __restrict__ h1, const float* __restrict__ W2,
                        float* __restrict__ Wx2) {
    __shared__ float hs[8 * HID];
    const int i0 = blockIdx.x * 8;
    const int t = threadIdx.x;
    for (int p = t; p < 8 * HID; p += 256) hs[p] = h1[i0 * HID + p];
    __syncthreads();
    float acc[8][4] = {};
    for (int k = 0; k < HID; k++) {
        float wv0 = W2[k * C2 + t];
        float wv1 = W2[k * C2 + 256 + t];
        float wv2 = W2[k * C2 + 512 + t];
        float wv3 = W2[k * C2 + 768 + t];
#pragma unroll
        for (int r = 0; r < 8; r++) {
            float a = hs[r * HID + k];
            acc[r][0] += a * wv0;
            acc[r][1] += a * wv1;
            acc[r][2] += a * wv2;
            acc[r][3] += a * wv3;
        }
    }
#pragma unroll
    for (int r = 0; r < 8; r++) {
        Wx2[(i0 + r) * C2 + t]       = acc[r][0];
        Wx2[(i0 + r) * C2 + 256 + t] = acc[r][1];
        Wx2[(i0 + r) * C2 + 512 + t] = acc[r][2];
        Wx2[(i0 + r) * C2 + 768 + t] = acc[r][3];
    }
}

// ---------------- per-node scores layer 1 ----------------
// es[h][i] = sum_d Wx1[i][h*64+d]*attn1[h][d]; et uses attn1[h][64+d]
__global__ void escore1_k(const float* __restrict__ Wx1, const float* __restrict__ attn1,
                          float* __restrict__ es, float* __restrict__ et) {
    const int i = blockIdx.x;
    const int t = threadIdx.x;
    const int h = t >> 6, l = t & 63;
    float v = Wx1[i * HID + t];
    float ps = v * attn1[h * 2 * D1 + l];
    float pt = v * attn1[h * 2 * D1 + D1 + l];
    ps = wave_sum(ps);
    pt = wave_sum(pt);
    if (l == 0) {
        es[h * NND + i] = ps;
        et[h * NND + i] = pt;
    }
}

// ---------------- per-node scores layer 2 (256-wide reduction per head) ----------------
__global__ void escore2_k(const float* __restrict__ Wx2, const float* __restrict__ attn2,
                          float* __restrict__ es, float* __restrict__ et) {
    __shared__ float red[8];
    const int i = blockIdx.x;
    const int t = threadIdx.x;
    const int wid = t >> 6, lane = t & 63;
    for (int h = 0; h < HEADS; h++) {
        float v = Wx2[i * C2 + h * D2 + t];
        float ps = v * attn2[h * 2 * D2 + t];
        float pt = v * attn2[h * 2 * D2 + D2 + t];
        ps = wave_sum(ps);
        pt = wave_sum(pt);
        if (lane == 0) { red[wid] = ps; red[4 + wid] = pt; }
        __syncthreads();
        if (t == 0) {
            es[h * NND + i] = red[0] + red[1] + red[2] + red[3];
            et[h * NND + i] = red[4] + red[5] + red[6] + red[7];
        }
        __syncthreads();
    }
}

// ---------------- bitonic sort of t per head (4096 elems in LDS) ----------------
__global__ void sort_k(const float* __restrict__ et, float* __restrict__ ts,
                       int* __restrict__ perm) {
    __shared__ float key[NND];
    __shared__ int idx[NND];
    const int h = blockIdx.x;
    const int t = threadIdx.x;
    for (int p = t; p < NND; p += 1024) { key[p] = et[h * NND + p]; idx[p] = p; }
    for (int size = 2; size <= NND; size <<= 1) {
        for (int stride = size >> 1; stride > 0; stride >>= 1) {
            __syncthreads();
            for (int n = t; n < NND / 2; n += 1024) {
                int i = ((n & ~(stride - 1)) << 1) | (n & (stride - 1));
                int j = i + stride;
                bool asc = ((i & size) == 0);
                float ki = key[i], kj = key[j];
                bool sw = asc ? (ki > kj) : (ki < kj);
                if (sw) {
                    key[i] = kj; key[j] = ki;
                    int tmp = idx[i]; idx[i] = idx[j]; idx[j] = tmp;
                }
            }
        }
    }
    __syncthreads();
    for (int p = t; p < NND; p += 1024) {
        ts[h * NND + p] = key[p];
        perm[h * NND + p] = idx[p];
    }
}

// ---------------- scan pass 1: per-(head,chunk) totals ----------------
// wA = exp(t - tmax) (full-slope branch), wB = exp(0.2*(t - tmax))
__global__ void scan_p1_k(const float* __restrict__ V, int rowStride,
                          const float* __restrict__ ts, const int* __restrict__ perm,
                          float* __restrict__ cTA, float* __restrict__ cTB,
                          float* __restrict__ cSA, float* __restrict__ cSB) {
    const int ch = blockIdx.x, h = blockIdx.y;
    const int d = threadIdx.x, D = blockDim.x;
    const float tmax = ts[h * NND + NND - 1];
    float aA = 0.f, aB = 0.f, aSA = 0.f, aSB = 0.f;
    const int k0 = ch * CHROWS;
    for (int r = 0; r < CHROWS; r++) {
        int k = k0 + r;
        float u = ts[h * NND + k] - tmax;
        float wA = expf(u);
        float wB = expf(LEAKY * u);
        int j = perm[h * NND + k];
        float v = V[j * rowStride + h * D + d];
        aA += wA * v; aB += wB * v; aSA += wA; aSB += wB;
    }
    cTA[(h * CH + ch) * 256 + d] = aA;
    cTB[(h * CH + ch) * 256 + d] = aB;
    if (d == 0) { cSA[h * CH + ch] = aSA; cSB[h * CH + ch] = aSB; }
}

// ---------------- scan pass 2: exclusive-scan chunk totals (in place) + grand totals ----------------
__global__ void scan_p2_k(float* __restrict__ cTA, float* __restrict__ cTB,
                          float* __restrict__ cSA, float* __restrict__ cSB,
                          float* __restrict__ TotA, float* __restrict__ TotB,
                          float* __restrict__ TotS, int D) {
    const int h = blockIdx.x;
    const int d = threadIdx.x;
    if (d < D) {
        float rA = 0.f, rB = 0.f;
        for (int ch = 0; ch < CH; ch++) {
            int o = (h * CH + ch) * 256 + d;
            float vA = cTA[o], vB = cTB[o];
            cTA[o] = rA; cTB[o] = rB;
            rA += vA; rB += vB;
        }
        TotA[h * 256 + d] = rA;
        TotB[h * 256 + d] = rB;
    }
    if (d == 0) {
        float rA = 0.f, rB = 0.f;
        for (int ch = 0; ch < CH; ch++) {
            float vA = cSA[h * CH + ch], vB = cSB[h * CH + ch];
            cSA[h * CH + ch] = rA; cSB[h * CH + ch] = rB;
            rA += vA; rB += vB;
        }
        TotS[h * 2] = rA; TotS[h * 2 + 1] = rB;
    }
}

// ---------------- scan pass 3: write full A (suffix incl. k) / B (prefix excl. k) arrays ----------------
__global__ void scan_p3_k(const float* __restrict__ V, int rowStride,
                          const float* __restrict__ ts, const int* __restrict__ perm,
                          const float* __restrict__ cTA, const float* __restrict__ cTB,
                          const float* __restrict__ cSA, const float* __restrict__ cSB,
                          const float* __restrict__ TotA, const float* __restrict__ TotB,
                          const float* __restrict__ TotS,
                          float* __restrict__ A, float* __restrict__ B,
                          float* __restrict__ SA, float* __restrict__ SB) {
    const int ch = blockIdx.x, h = blockIdx.y;
    const int d = threadIdx.x, D = blockDim.x;
    const float tmax = ts[h * NND + NND - 1];
    float runA = cTA[(h * CH + ch) * 256 + d];
    float runB = cTB[(h * CH + ch) * 256 + d];
    float runSA = cSA[h * CH + ch];
    float runSB = cSB[h * CH + ch];
    const float totA = TotA[h * 256 + d];
    const float totB = TotB[h * 256 + d];
    const float totSA = TotS[h * 2];
    const float totSB = TotS[h * 2 + 1];
    const int k0 = ch * CHROWS;
    for (int r = 0; r < CHROWS; r++) {
        int k = k0 + r;
        float u = ts[h * NND + k] - tmax;
        float wA = expf(u);
        float wB = expf(LEAKY * u);
        int j = perm[h * NND + k];
        float v = V[j * rowStride + h * D + d];
        size_t o = ((size_t)(h * NP1 + k)) * D + d;
        A[o] = totA - runA;   // suffix sum including k
        B[o] = runB;          // prefix sum excluding k
        if (d == 0) {
            SA[h * NP1 + k] = totSA - runSA;
            SB[h * NP1 + k] = runSB;
        }
        runA += wA * v;
        runB += wB * v;
        runSA += wA;
        runSB += wB;
    }
    if (ch == CH - 1) {
        size_t o = ((size_t)(h * NP1 + NND)) * D + d;
        A[o] = totA - runA;   // ~0
        B[o] = runB;          // total B
        if (d == 0) {
            SA[h * NP1 + NND] = totSA - runSA;
            SB[h * NP1 + NND] = runSB;
        }
    }
}

// ---------------- lookup layer 1: combine + ELU -> h1 ----------------
__global__ void lookup1_k(const float* __restrict__ es, const float* __restrict__ ts,
                          const float* __restrict__ A, const float* __restrict__ B,
                          const float* __restrict__ SA, const float* __restrict__ SB,
                          float* __restrict__ h1) {
    const int i = blockIdx.x;
    const int t = threadIdx.x;
    const int h = t >> 6, d = t & 63;
    float c = es[h * NND + i];
    float tmax = ts[h * NND + NND - 1];
    float s = c + tmax;
    float m = (s >= 0.f) ? s : LEAKY * s;
    float al = expf(s - m);            // <= 1
    float be = expf(LEAKY * s - m);    // <= 1
    int k = lower_bound_f(ts + h * NND, -c);
    size_t o = ((size_t)(h * NP1 + k)) * D1 + d;
    float num = al * A[o] + be * B[o];
    float den = al * SA[h * NP1 + k] + be * SB[h * NP1 + k];
    float val = num / den;
    h1[i * HID + t] = (val > 0.f) ? val : expm1f(val);
}

// ---------------- lookup layer 2: combine + head-mean + ELU + LayerNorm -> out ----------------
__global__ void lookup2_k(const float* __restrict__ es, const float* __restrict__ ts,
                          const float* __restrict__ A, const float* __restrict__ B,
                          const float* __restrict__ SA, const float* __restrict__ SB,
                          const float* __restrict__ gamma, const float* __restrict__ betap,
                          float* __restrict__ out) {
    __shared__ float red[4];
    const int i = blockIdx.x;
    const int t = threadIdx.x;
    const int wid = t >> 6, lane = t & 63;
    float acc = 0.f;
    for (int h = 0; h < HEADS; h++) {
        float c = es[h * NND + i];
        float tmax = ts[h * NND + NND - 1];
        float s = c + tmax;
        float m = (s >= 0.f) ? s : LEAKY * s;
        float al = expf(s - m);
        float be = expf(LEAKY * s - m);
        int k = lower_bound_f(ts + h * NND, -c);
        size_t o = ((size_t)(h * NP1 + k)) * D2 + t;
        float num = al * A[o] + be * B[o];
        float den = al * SA[h * NP1 + k] + be * SB[h * NP1 + k];
        acc += num / den;
    }
    acc *= 0.25f;
    float xv = (acc > 0.f) ? acc : expm1f(acc);
    // LayerNorm over 256 dims
    float sv = wave_sum(xv);
    if (lane == 0) red[wid] = sv;
    __syncthreads();
    float mu = (red[0] + red[1] + red[2] + red[3]) * (1.f / 256.f);
    __syncthreads();
    float dv = xv - mu;
    float s2 = wave_sum(dv * dv);
    if (lane == 0) red[wid] = s2;
    __syncthreads();
    float var = (red[0] + red[1] + red[2] + red[3]) * (1.f / 256.f);
    out[i * D2 + t] = gamma[t] * dv * rsqrtf(var + LN_EPS) + betap[t];
}

extern "C" void kernel_launch(void* const* d_in, const int* in_sizes, int n_in,
                              void* d_out, int out_size, void* d_ws, size_t ws_size,
                              hipStream_t stream) {
    const float* x     = (const float*)d_in[0];
    const float* W1    = (const float*)d_in[1];
    const float* attn1 = (const float*)d_in[2];
    const float* W2    = (const float*)d_in[3];
    const float* attn2 = (const float*)d_in[4];
    const float* gamma = (const float*)d_in[5];
    const float* betap = (const float*)d_in[6];
    float* out = (float*)d_out;

    char* ws = (char*)d_ws;
    size_t off = 0;
    auto alloc = [&](size_t nbytes) -> void* {
        void* p = (void*)(ws + off);
        off += (nbytes + 255) & ~(size_t)255;
        return p;
    };

    float* Wx1 = (float*)alloc((size_t)NND * HID * 4);
    float* Wx2 = (float*)alloc((size_t)NND * C2 * 4);
    float* h1  = (float*)alloc((size_t)NND * HID * 4);
    float* es1 = (float*)alloc((size_t)HEADS * NND * 4);
    float* et1 = (float*)alloc((size_t)HEADS * NND * 4);
    float* es2 = (float*)alloc((size_t)HEADS * NND * 4);
    float* et2 = (float*)alloc((size_t)HEADS * NND * 4);
    float* ts1 = (float*)alloc((size_t)HEADS * NND * 4);
    float* ts2 = (float*)alloc((size_t)HEADS * NND * 4);
    int* perm1 = (int*)alloc((size_t)HEADS * NND * 4);
    int* perm2 = (int*)alloc((size_t)HEADS * NND * 4);
    // A/B sized for layer 2 (D2=256); layer 1 reuses the same buffers with D1 indexing
    float* A   = (float*)alloc((size_t)HEADS * NP1 * D2 * 4);
    float* B   = (float*)alloc((size_t)HEADS * NP1 * D2 * 4);
    float* SA  = (float*)alloc((size_t)HEADS * NP1 * 4);
    float* SB  = (float*)alloc((size_t)HEADS * NP1 * 4);
    float* cTA = (float*)alloc((size_t)HEADS * CH * 256 * 4);
    float* cTB = (float*)alloc((size_t)HEADS * CH * 256 * 4);
    float* cSA = (float*)alloc((size_t)HEADS * CH * 4);
    float* cSB = (float*)alloc((size_t)HEADS * CH * 4);
    float* TotA = (float*)alloc((size_t)HEADS * 256 * 4);
    float* TotB = (float*)alloc((size_t)HEADS * 256 * 4);
    float* TotS = (float*)alloc((size_t)HEADS * 2 * 4);
    (void)ws_size; (void)in_sizes; (void)n_in; (void)out_size;

    dim3 gScan(CH, HEADS);

    // ---- layer 1 ----
    gemm1_k<<<NND / 8, 256, 0, stream>>>(x, W1, Wx1);
    escore1_k<<<NND, 256, 0, stream>>>(Wx1, attn1, es1, et1);
    sort_k<<<HEADS, 1024, 0, stream>>>(et1, ts1, perm1);
    scan_p1_k<<<gScan, D1, 0, stream>>>(Wx1, HID, ts1, perm1, cTA, cTB, cSA, cSB);
    scan_p2_k<<<HEADS, 256, 0, stream>>>(cTA, cTB, cSA, cSB, TotA, TotB, TotS, D1);
    scan_p3_k<<<gScan, D1, 0, stream>>>(Wx1, HID, ts1, perm1, cTA, cTB, cSA, cSB,
                                        TotA, TotB, TotS, A, B, SA, SB);
    lookup1_k<<<NND, 256, 0, stream>>>(es1, ts1, A, B, SA, SB, h1);

    // ---- layer 2 ----
    gemm2_k<<<NND / 8, 256, 0, stream>>>(h1, W2, Wx2);
    escore2_k<<<NND, 256, 0, stream>>>(Wx2, attn2, es2, et2);
    sort_k<<<HEADS, 1024, 0, stream>>>(et2, ts2, perm2);
    scan_p1_k<<<gScan, D2, 0, stream>>>(Wx2, C2, ts2, perm2, cTA, cTB, cSA, cSB);
    scan_p2_k<<<HEADS, 256, 0, stream>>>(cTA, cTB, cSA, cSB, TotA, TotB, TotS, D2);
    scan_p3_k<<<gScan, D2, 0, stream>>>(Wx2, C2, ts2, perm2, cTA, cTB, cSA, cSB,
                                        TotA, TotB, TotS, A, B, SA, SB);
    lookup2_k<<<NND, 256, 0, stream>>>(es2, ts2, A, B, SA, SB, gamma, betap, out);
}

// Round 2
// 238.344 us; speedup vs baseline: 1.6411x; 1.6411x over previous
//
#include <hip/hip_runtime.h>
#include <math.h>

#define NND 4096
#define SDIM 128
#define HEADS 4
#define D1 64
#define HID 256
#define D2 256
#define C2 1024
#define NP1 (NND + 1)
#define CH 128
#define CHR 32
#define LEAKY 0.2f
#define LN_EPS 1e-5f

__device__ __forceinline__ float wave_sum(float v) {
#pragma unroll
    for (int o = 32; o > 0; o >>= 1) v += __shfl_xor(v, o, 64);
    return v;
}

__device__ __forceinline__ int lower_bound_f(const float* __restrict__ a, float x) {
    int lo = 0, hi = NND;
    while (lo < hi) {
        int mid = (lo + hi) >> 1;
        if (a[mid] < x) lo = mid + 1; else hi = mid;
    }
    return lo;
}

// ---------------- tiled fp32 GEMM: C(MxN) = A(MxK) @ B(KxN) ----------------
// 64x64 tile, BK=32, 256 threads, 4x4 micro-tile per thread.
__global__ void gemm_tile_k(const float* __restrict__ Ag, const float* __restrict__ Bg,
                            float* __restrict__ Cg, int M, int N, int K) {
    __shared__ float As[32][68];   // [k][m], +4 pad keeps 16B alignment, spreads banks
    __shared__ float Bs[32][68];   // [k][n]
    const int t = threadIdx.x;
    const int m0 = blockIdx.y * 64;
    const int n0 = blockIdx.x * 64;
    const int tn = t & 15, tm = t >> 4;
    float acc[4][4] = {};
    for (int k0 = 0; k0 < K; k0 += 32) {
#pragma unroll
        for (int q = 0; q < 2; q++) {
            int p = t + 256 * q;            // 0..511
            int r  = p >> 3;                // 0..63  (A row)
            int kk = (p & 7) * 4;           // 0..28  (A k)
            float4 av = *(const float4*)&Ag[(size_t)(m0 + r) * K + k0 + kk];
            As[kk + 0][r] = av.x; As[kk + 1][r] = av.y;
            As[kk + 2][r] = av.z; As[kk + 3][r] = av.w;
            int kr = p >> 4;                // 0..31  (B k)
            int c  = (p & 15) * 4;          // 0..60  (B col)
            float4 bv = *(const float4*)&Bg[(size_t)(k0 + kr) * N + n0 + c];
            *(float4*)&Bs[kr][c] = bv;
        }
        __syncthreads();
#pragma unroll
        for (int kk = 0; kk < 32; kk++) {
            float4 a = *(const float4*)&As[kk][tm * 4];
            float4 b = *(const float4*)&Bs[kk][tn * 4];
            float af[4] = {a.x, a.y, a.z, a.w};
            float bf[4] = {b.x, b.y, b.z, b.w};
#pragma unroll
            for (int m = 0; m < 4; m++)
#pragma unroll
                for (int n = 0; n < 4; n++) acc[m][n] += af[m] * bf[n];
        }
        __syncthreads();
    }
#pragma unroll
    for (int m = 0; m < 4; m++) {
        float4 o = make_float4(acc[m][0], acc[m][1], acc[m][2], acc[m][3]);
        *(float4*)&Cg[(size_t)(m0 + tm * 4 + m) * N + n0 + tn * 4] = o;
    }
}

// ---------------- per-node scores layer 1 ----------------
__global__ void escore1_k(const float* __restrict__ Wx1, const float* __restrict__ attn1,
                          float* __restrict__ es, float* __restrict__ et) {
    const int i = blockIdx.x;
    const int t = threadIdx.x;
    const int h = t >> 6, l = t & 63;
    float v = Wx1[i * HID + t];
    float ps = v * attn1[h * 2 * D1 + l];
    float pt = v * attn1[h * 2 * D1 + D1 + l];
    ps = wave_sum(ps);
    pt = wave_sum(pt);
    if (l == 0) {
        es[h * NND + i] = ps;
        et[h * NND + i] = pt;
    }
}

// ---------------- per-node scores layer 2 ----------------
__global__ void escore2_k(const float* __restrict__ Wx2, const float* __restrict__ attn2,
                          float* __restrict__ es, float* __restrict__ et) {
    __shared__ float red[8];
    const int i = blockIdx.x;
    const int t = threadIdx.x;
    const int wid = t >> 6, lane = t & 63;
    for (int h = 0; h < HEADS; h++) {
        float v = Wx2[i * C2 + h * D2 + t];
        float ps = v * attn2[h * 2 * D2 + t];
        float pt = v * attn2[h * 2 * D2 + D2 + t];
        ps = wave_sum(ps);
        pt = wave_sum(pt);
        if (lane == 0) { red[wid] = ps; red[4 + wid] = pt; }
        __syncthreads();
        if (t == 0) {
            es[h * NND + i] = red[0] + red[1] + red[2] + red[3];
            et[h * NND + i] = red[4] + red[5] + red[6] + red[7];
        }
        __syncthreads();
    }
}

// ---------------- rank-based sort: rank = #smaller (+ tie-break on index) ----------------
// grid (NND/64, HEADS), 256 threads: 64 elements/block, 4 key-segments/element.
__global__ void rank_sort_k(const float* __restrict__ et, float* __restrict__ ts,
                            int* __restrict__ perm) {
    __shared__ float key[NND];
    __shared__ int pr[64];
    const int h = blockIdx.y;
    const int e0 = blockIdx.x * 64;
    const int t = threadIdx.x;
    const int e = t & 63, sg = t >> 6;
    for (int p = t; p < NND; p += 256) key[p] = et[h * NND + p];
    if (t < 64) pr[t] = 0;
    __syncthreads();
    const int myIdx = e0 + e;
    const float myV = key[myIdx];
    int rank = 0;
    const int kbeg = sg * (NND / 4);
#pragma unroll 4
    for (int k = kbeg; k < kbeg + NND / 4; k++) {
        float v = key[k];
        rank += (v < myV || (v == myV && k < myIdx)) ? 1 : 0;
    }
    atomicAdd(&pr[e], rank);
    __syncthreads();
    if (t < 64) {
        int r = pr[t];
        ts[h * NND + r] = key[e0 + t];
        perm[h * NND + r] = e0 + t;
    }
}

// ---------------- layer-1 scan pass 1 (heads folded: 256 thr = 4h x 64d) ----------------
__global__ void scan1_p1_k(const float* __restrict__ V, const float* __restrict__ ts,
                           const int* __restrict__ perm,
                           float* __restrict__ cTA, float* __restrict__ cTB,
                           float* __restrict__ cSA, float* __restrict__ cSB) {
    const int ch = blockIdx.x;
    const int t = threadIdx.x;
    const int h = t >> 6, d = t & 63;
    const float tmax = ts[h * NND + NND - 1];
    float aA = 0.f, aB = 0.f, aSA = 0.f, aSB = 0.f;
    const int k0 = ch * CHR;
    for (int r = 0; r < CHR; r++) {
        int k = k0 + r;
        float u = ts[h * NND + k] - tmax;
        float wA = expf(u);
        float wB = expf(LEAKY * u);
        int j = perm[h * NND + k];
        float v = V[j * HID + h * D1 + d];
        aA += wA * v; aB += wB * v; aSA += wA; aSB += wB;
    }
    cTA[(h * CH + ch) * D1 + d] = aA;
    cTB[(h * CH + ch) * D1 + d] = aB;
    if (d == 0) { cSA[h * CH + ch] = aSA; cSB[h * CH + ch] = aSB; }
}

// ---------------- layer-2 scan pass 1 (grid: CH x HEADS, 256 thr = d) ----------------
__global__ void scan2_p1_k(const float* __restrict__ V, const float* __restrict__ ts,
                           const int* __restrict__ perm,
                           float* __restrict__ cTA, float* __restrict__ cTB,
                           float* __restrict__ cSA, float* __restrict__ cSB) {
    const int ch = blockIdx.x, h = blockIdx.y;
    const int d = threadIdx.x;
    const float tmax = ts[h * NND + NND - 1];
    float aA = 0.f, aB = 0.f, aSA = 0.f, aSB = 0.f;
    const int k0 = ch * CHR;
    for (int r = 0; r < CHR; r++) {
        int k = k0 + r;
        float u = ts[h * NND + k] - tmax;
        float wA = expf(u);
        float wB = expf(LEAKY * u);
        int j = perm[h * NND + k];
        float v = V[j * C2 + h * D2 + d];
        aA += wA * v; aB += wB * v; aSA += wA; aSB += wB;
    }
    cTA[(h * CH + ch) * D2 + d] = aA;
    cTB[(h * CH + ch) * D2 + d] = aB;
    if (d == 0) { cSA[h * CH + ch] = aSA; cSB[h * CH + ch] = aSB; }
}

// ---------------- scan pass 2: exclusive-scan chunk totals (in place) ----------------
__global__ void scan_p2_k(float* __restrict__ cTA, float* __restrict__ cTB,
                          float* __restrict__ cSA, float* __restrict__ cSB,
                          float* __restrict__ TotA, float* __restrict__ TotB,
                          float* __restrict__ TotS, int D) {
    const int h = blockIdx.x;
    const int d = threadIdx.x;
    if (d < D) {
        float rA = 0.f, rB = 0.f;
#pragma unroll 8
        for (int ch = 0; ch < CH; ch++) {
            int o = (h * CH + ch) * D + d;
            float vA = cTA[o], vB = cTB[o];
            cTA[o] = rA; cTB[o] = rB;
            rA += vA; rB += vB;
        }
        TotA[h * 256 + d] = rA;
        TotB[h * 256 + d] = rB;
    }
    if (d == 0) {
        float rA = 0.f, rB = 0.f;
#pragma unroll 8
        for (int ch = 0; ch < CH; ch++) {
            float vA = cSA[h * CH + ch], vB = cSB[h * CH + ch];
            cSA[h * CH + ch] = rA; cSB[h * CH + ch] = rB;
            rA += vA; rB += vB;
        }
        TotS[h * 2] = rA; TotS[h * 2 + 1] = rB;
    }
}

// ---------------- layer-1 scan pass 3 (heads folded) ----------------
__global__ void scan1_p3_k(const float* __restrict__ V, const float* __restrict__ ts,
                           const int* __restrict__ perm,
                           const float* __restrict__ cTA, const float* __restrict__ cTB,
                           const float* __restrict__ cSA, const float* __restrict__ cSB,
                           const float* __restrict__ TotA, const float* __restrict__ TotB,
                           const float* __restrict__ TotS,
                           float* __restrict__ A, float* __restrict__ B,
                           float* __restrict__ SA, float* __restrict__ SB) {
    const int ch = blockIdx.x;
    const int t = threadIdx.x;
    const int h = t >> 6, d = t & 63;
    const float tmax = ts[h * NND + NND - 1];
    float runA = cTA[(h * CH + ch) * D1 + d];
    float runB = cTB[(h * CH + ch) * D1 + d];
    float runSA = cSA[h * CH + ch];
    float runSB = cSB[h * CH + ch];
    const float totA = TotA[h * 256 + d];
    const float totB = TotB[h * 256 + d];
    const float totSA = TotS[h * 2];
    const float totSB = TotS[h * 2 + 1];
    const int k0 = ch * CHR;
    for (int r = 0; r < CHR; r++) {
        int k = k0 + r;
        float u = ts[h * NND + k] - tmax;
        float wA = expf(u);
        float wB = expf(LEAKY * u);
        int j = perm[h * NND + k];
        float v = V[j * HID + h * D1 + d];
        size_t o = ((size_t)(h * NP1 + k)) * D1 + d;
        A[o] = totA - runA;
        B[o] = runB;
        if (d == 0) {
            SA[h * NP1 + k] = totSA - runSA;
            SB[h * NP1 + k] = runSB;
        }
        runA += wA * v; runB += wB * v; runSA += wA; runSB += wB;
    }
    if (ch == CH - 1) {
        size_t o = ((size_t)(h * NP1 + NND)) * D1 + d;
        A[o] = totA - runA;
        B[o] = runB;
        if (d == 0) {
            SA[h * NP1 + NND] = totSA - runSA;
            SB[h * NP1 + NND] = runSB;
        }
    }
}

// ---------------- layer-2 scan pass 3 ----------------
__global__ void scan2_p3_k(const float* __restrict__ V, const float* __restrict__ ts,
                           const int* __restrict__ perm,
                           const float* __restrict__ cTA, const float* __restrict__ cTB,
                           const float* __restrict__ cSA, const float* __restrict__ cSB,
                           const float* __restrict__ TotA, const float* __restrict__ TotB,
                           const float* __restrict__ TotS,
                           float* __restrict__ A, float* __restrict__ B,
                           float* __restrict__ SA, float* __restrict__ SB) {
    const int ch = blockIdx.x, h = blockIdx.y;
    const int d = threadIdx.x;
    const float tmax = ts[h * NND + NND - 1];
    float runA = cTA[(h * CH + ch) * D2 + d];
    float runB = cTB[(h * CH + ch) * D2 + d];
    float runSA = cSA[h * CH + ch];
    float runSB = cSB[h * CH + ch];
    const float totA = TotA[h * 256 + d];
    const float totB = TotB[h * 256 + d];
    const float totSA = TotS[h * 2];
    const float totSB = TotS[h * 2 + 1];
    const int k0 = ch * CHR;
    for (int r = 0; r < CHR; r++) {
        int k = k0 + r;
        float u = ts[h * NND + k] - tmax;
        float wA = expf(u);
        float wB = expf(LEAKY * u);
        int j = perm[h * NND + k];
        float v = V[j * C2 + h * D2 + d];
        size_t o = ((size_t)(h * NP1 + k)) * D2 + d;
        A[o] = totA - runA;
        B[o] = runB;
        if (d == 0) {
            SA[h * NP1 + k] = totSA - runSA;
            SB[h * NP1 + k] = runSB;
        }
        runA += wA * v; runB += wB * v; runSA += wA; runSB += wB;
    }
    if (ch == CH - 1) {
        size_t o = ((size_t)(h * NP1 + NND)) * D2 + d;
        A[o] = totA - runA;
        B[o] = runB;
        if (d == 0) {
            SA[h * NP1 + NND] = totSA - runSA;
            SB[h * NP1 + NND] = runSB;
        }
    }
}

// ---------------- lookup layer 1: combine + ELU -> h1 ----------------
__global__ void lookup1_k(const float* __restrict__ es, const float* __restrict__ ts,
                          const float* __restrict__ A, const float* __restrict__ B,
                          const float* __restrict__ SA, const float* __restrict__ SB,
                          float* __restrict__ h1) {
    const int i = blockIdx.x;
    const int t = threadIdx.x;
    const int h = t >> 6, d = t & 63;
    float c = es[h * NND + i];
    float tmax = ts[h * NND + NND - 1];
    float s = c + tmax;
    float m = (s >= 0.f) ? s : LEAKY * s;
    float al = expf(s - m);
    float be = expf(LEAKY * s - m);
    int k = lower_bound_f(ts + h * NND, -c);
    size_t o = ((size_t)(h * NP1 + k)) * D1 + d;
    float num = al * A[o] + be * B[o];
    float den = al * SA[h * NP1 + k] + be * SB[h * NP1 + k];
    float val = num / den;
    h1[i * HID + t] = (val > 0.f) ? val : expm1f(val);
}

// ---------------- lookup layer 2: combine + head-mean + ELU + LayerNorm ----------------
__global__ void lookup2_k(const float* __restrict__ es, const float* __restrict__ ts,
                          const float* __restrict__ A, const float* __restrict__ B,
                          const float* __restrict__ SA, const float* __restrict__ SB,
                          const float* __restrict__ gamma, const float* __restrict__ betap,
                          float* __restrict__ out) {
    __shared__ float red[4];
    const int i = blockIdx.x;
    const int t = threadIdx.x;
    const int wid = t >> 6, lane = t & 63;
    float acc = 0.f;
    for (int h = 0; h < HEADS; h++) {
        float c = es[h * NND + i];
        float tmax = ts[h * NND + NND - 1];
        float s = c + tmax;
        float m = (s >= 0.f) ? s : LEAKY * s;
        float al = expf(s - m);
        float be = expf(LEAKY * s - m);
        int k = lower_bound_f(ts + h * NND, -c);
        size_t o = ((size_t)(h * NP1 + k)) * D2 + t;
        float num = al * A[o] + be * B[o];
        float den = al * SA[h * NP1 + k] + be * SB[h * NP1 + k];
        acc += num / den;
    }
    acc *= 0.25f;
    float xv = (acc > 0.f) ? acc : expm1f(acc);
    float sv = wave_sum(xv);
    if (lane == 0) red[wid] = sv;
    __syncthreads();
    float mu = (red[0] + red[1] + red[2] + red[3]) * (1.f / 256.f);
    __syncthreads();
    float dv = xv - mu;
    float s2 = wave_sum(dv * dv);
    if (lane == 0) red[wid] = s2;
    __syncthreads();
    float var = (red[0] + red[1] + red[2] + red[3]) * (1.f / 256.f);
    out[i * D2 + t] = gamma[t] * dv * rsqrtf(var + LN_EPS) + betap[t];
}

extern "C" void kernel_launch(void* const* d_in, const int* in_sizes, int n_in,
                              void* d_out, int out_size, void* d_ws, size_t ws_size,
                              hipStream_t stream) {
    const float* x     = (const float*)d_in[0];
    const float* W1    = (const float*)d_in[1];
    const float* attn1 = (const float*)d_in[2];
    const float* W2    = (const float*)d_in[3];
    const float* attn2 = (const float*)d_in[4];
    const float* gamma = (const float*)d_in[5];
    const float* betap = (const float*)d_in[6];
    float* out = (float*)d_out;

    char* ws = (char*)d_ws;
    size_t off = 0;
    auto alloc = [&](size_t nbytes) -> void* {
        void* p = (void*)(ws + off);
        off += (nbytes + 255) & ~(size_t)255;
        return p;
    };

    float* Wx1 = (float*)alloc((size_t)NND * HID * 4);
    float* Wx2 = (float*)alloc((size_t)NND * C2 * 4);
    float* h1  = (float*)alloc((size_t)NND * HID * 4);
    float* es1 = (float*)alloc((size_t)HEADS * NND * 4);
    float* et1 = (float*)alloc((size_t)HEADS * NND * 4);
    float* es2 = (float*)alloc((size_t)HEADS * NND * 4);
    float* et2 = (float*)alloc((size_t)HEADS * NND * 4);
    float* ts1 = (float*)alloc((size_t)HEADS * NND * 4);
    float* ts2 = (float*)alloc((size_t)HEADS * NND * 4);
    int* perm1 = (int*)alloc((size_t)HEADS * NND * 4);
    int* perm2 = (int*)alloc((size_t)HEADS * NND * 4);
    float* A   = (float*)alloc((size_t)HEADS * NP1 * D2 * 4);
    float* B   = (float*)alloc((size_t)HEADS * NP1 * D2 * 4);
    float* SA  = (float*)alloc((size_t)HEADS * NP1 * 4);
    float* SB  = (float*)alloc((size_t)HEADS * NP1 * 4);
    float* cTA = (float*)alloc((size_t)HEADS * CH * 256 * 4);
    float* cTB = (float*)alloc((size_t)HEADS * CH * 256 * 4);
    float* cSA = (float*)alloc((size_t)HEADS * CH * 4);
    float* cSB = (float*)alloc((size_t)HEADS * CH * 4);
    float* TotA = (float*)alloc((size_t)HEADS * 256 * 4);
    float* TotB = (float*)alloc((size_t)HEADS * 256 * 4);
    float* TotS = (float*)alloc((size_t)HEADS * 2 * 4);
    (void)ws_size; (void)in_sizes; (void)n_in; (void)out_size;

    dim3 gScan2(CH, HEADS);
    dim3 gSort(NND / 64, HEADS);

    // ---- layer 1 ----
    gemm_tile_k<<<dim3(HID / 64, NND / 64), 256, 0, stream>>>(x, W1, Wx1, NND, HID, SDIM);
    escore1_k<<<NND, 256, 0, stream>>>(Wx1, attn1, es1, et1);
    rank_sort_k<<<gSort, 256, 0, stream>>>(et1, ts1, perm1);
    scan1_p1_k<<<CH, 256, 0, stream>>>(Wx1, ts1, perm1, cTA, cTB, cSA, cSB);
    scan_p2_k<<<HEADS, 256, 0, stream>>>(cTA, cTB, cSA, cSB, TotA, TotB, TotS, D1);
    scan1_p3_k<<<CH, 256, 0, stream>>>(Wx1, ts1, perm1, cTA, cTB, cSA, cSB,
                                       TotA, TotB, TotS, A, B, SA, SB);
    lookup1_k<<<NND, 256, 0, stream>>>(es1, ts1, A, B, SA, SB, h1);

    // ---- layer 2 ----
    gemm_tile_k<<<dim3(C2 / 64, NND / 64), 256, 0, stream>>>(h1, W2, Wx2, NND, C2, HID);
    escore2_k<<<NND, 256, 0, stream>>>(Wx2, attn2, es2, et2);
    rank_sort_k<<<gSort, 256, 0, stream>>>(et2, ts2, perm2);
    scan2_p1_k<<<gScan2, 256, 0, stream>>>(Wx2, ts2, perm2, cTA, cTB, cSA, cSB);
    scan_p2_k<<<HEADS, 256, 0, stream>>>(cTA, cTB, cSA, cSB, TotA, TotB, TotS, D2);
    scan2_p3_k<<<gScan2, 256, 0, stream>>>(Wx2, ts2, perm2, cTA, cTB, cSA, cSB,
                                           TotA, TotB, TotS, A, B, SA, SB);
    lookup2_k<<<NND, 256, 0, stream>>>(es2, ts2, A, B, SA, SB, gamma, betap, out);
}

// Round 3
// 232.379 us; speedup vs baseline: 1.6832x; 1.0257x over previous
//
#include <hip/hip_runtime.h>
#include <math.h>

#define NND 4096
#define SDIM 128
#define HEADS 4
#define D1 64
#define HID 256
#define D2 256
#define C2 1024
#define NP1 (NND + 1)
#define CH1 128
#define CHR1 32
#define CH2 64
#define CHR2 64
#define LEAKY 0.2f
#define LN_EPS 1e-5f
#define LDA 40

typedef __attribute__((ext_vector_type(8))) short bf16x8;
typedef __attribute__((ext_vector_type(4))) float f32x4;
typedef __attribute__((ext_vector_type(8))) unsigned short u16x8;
typedef __attribute__((ext_vector_type(4))) unsigned short u16x4;

__device__ __forceinline__ unsigned short f2bf(float f) {
    union { float f; unsigned u; } v; v.f = f;
    unsigned r = v.u + 0x7FFFu + ((v.u >> 16) & 1u);
    return (unsigned short)(r >> 16);
}
__device__ __forceinline__ float bf2f(unsigned short s) {
    union { unsigned u; float f; } v; v.u = ((unsigned)s) << 16; return v.f;
}

__device__ __forceinline__ float wave_sum(float v) {
#pragma unroll
    for (int o = 32; o > 0; o >>= 1) v += __shfl_xor(v, o, 64);
    return v;
}

__device__ __forceinline__ int lower_bound_f(const float* __restrict__ a, float x) {
    int lo = 0, hi = NND;
    while (lo < hi) {
        int mid = (lo + hi) >> 1;
        if (a[mid] < x) lo = mid + 1; else hi = mid;
    }
    return lo;
}

// ---------------- prep: transpose W1,W2 -> bf16 hi/lo [n][k] ----------------
__global__ void prep_w_k(const float* __restrict__ W1, const float* __restrict__ W2,
                         unsigned short* __restrict__ W1h, unsigned short* __restrict__ W1l,
                         unsigned short* __restrict__ W2h, unsigned short* __restrict__ W2l) {
    int id = blockIdx.x * 256 + threadIdx.x;
    if (id < 32768) {
        int n = id >> 7, k = id & 127;
        float v = W1[k * HID + n];
        unsigned short hi = f2bf(v);
        W1h[id] = hi; W1l[id] = f2bf(v - bf2f(hi));
    } else {
        int j = id - 32768;      // < 262144
        int n = j >> 8, k = j & 255;
        float v = W2[k * C2 + n];
        unsigned short hi = f2bf(v);
        W2h[j] = hi; W2l[j] = f2bf(v - bf2f(hi));
    }
}

#define MM(a, b, c) c = __builtin_amdgcn_mfma_f32_16x16x32_bf16(a, b, c, 0, 0, 0)

// ---------------- GEMM1 (MFMA split-bf16) + fused escore1 ----------------
// Wx1 = x(4096x128) @ W1(128x256); block = 64x64 tile; blockIdx.x == head.
__global__ __launch_bounds__(256) void gemm1_k(
        const float* __restrict__ x,
        const unsigned short* __restrict__ Wh, const unsigned short* __restrict__ Wl,
        const float* __restrict__ attn1,
        float* __restrict__ Wx1, float* __restrict__ es, float* __restrict__ et) {
    __shared__ unsigned short Ah[64][LDA], Al[64][LDA], Bh[64][LDA], Bl[64][LDA];
    __shared__ float esP[2][2][32], etP[2][2][32];
    const int t = threadIdx.x, lane = t & 63, w = t >> 6;
    const int wm = w >> 1, wn = w & 1;
    const int h = blockIdx.x, n0 = h * 64, m0 = blockIdx.y * 64;
    const int fr = lane & 15, kg = lane >> 4;
    f32x4 z4 = {0.f, 0.f, 0.f, 0.f};
    f32x4 acc[2][2] = {{z4, z4}, {z4, z4}};
    for (int k0 = 0; k0 < SDIM; k0 += 32) {
#pragma unroll
        for (int q = 0; q < 2; q++) {
            int p = t + 256 * q, r = p >> 3, kq = (p & 7) * 4;
            float4 av = *(const float4*)&x[(size_t)(m0 + r) * SDIM + k0 + kq];
            float fv[4] = {av.x, av.y, av.z, av.w};
            unsigned short hi[4], lo[4];
#pragma unroll
            for (int i = 0; i < 4; i++) { hi[i] = f2bf(fv[i]); lo[i] = f2bf(fv[i] - bf2f(hi[i])); }
            *(u16x4*)&Ah[r][kq] = (u16x4){hi[0], hi[1], hi[2], hi[3]};
            *(u16x4*)&Al[r][kq] = (u16x4){lo[0], lo[1], lo[2], lo[3]};
        }
        {
            int r = t >> 2, kq = (t & 3) * 8;
            *(u16x8*)&Bh[r][kq] = *(const u16x8*)&Wh[(size_t)(n0 + r) * SDIM + k0 + kq];
            *(u16x8*)&Bl[r][kq] = *(const u16x8*)&Wl[(size_t)(n0 + r) * SDIM + k0 + kq];
        }
        __syncthreads();
        bf16x8 ah0 = *(bf16x8*)&Ah[wm * 32 + fr][kg * 8];
        bf16x8 ah1 = *(bf16x8*)&Ah[wm * 32 + 16 + fr][kg * 8];
        bf16x8 al0 = *(bf16x8*)&Al[wm * 32 + fr][kg * 8];
        bf16x8 al1 = *(bf16x8*)&Al[wm * 32 + 16 + fr][kg * 8];
        bf16x8 bh0 = *(bf16x8*)&Bh[wn * 32 + fr][kg * 8];
        bf16x8 bh1 = *(bf16x8*)&Bh[wn * 32 + 16 + fr][kg * 8];
        bf16x8 bl0 = *(bf16x8*)&Bl[wn * 32 + fr][kg * 8];
        bf16x8 bl1 = *(bf16x8*)&Bl[wn * 32 + 16 + fr][kg * 8];
        MM(ah0, bh0, acc[0][0]); MM(ah0, bl0, acc[0][0]); MM(al0, bh0, acc[0][0]);
        MM(ah0, bh1, acc[0][1]); MM(ah0, bl1, acc[0][1]); MM(al0, bh1, acc[0][1]);
        MM(ah1, bh0, acc[1][0]); MM(ah1, bl0, acc[1][0]); MM(al1, bh0, acc[1][0]);
        MM(ah1, bh1, acc[1][1]); MM(ah1, bl1, acc[1][1]); MM(al1, bh1, acc[1][1]);
        __syncthreads();
    }
    const float as0 = attn1[h * 128 + wn * 32 + fr];
    const float as1 = attn1[h * 128 + wn * 32 + 16 + fr];
    const float at0 = attn1[h * 128 + 64 + wn * 32 + fr];
    const float at1 = attn1[h * 128 + 64 + wn * 32 + 16 + fr];
#pragma unroll
    for (int mb = 0; mb < 2; mb++) {
#pragma unroll
        for (int r = 0; r < 4; r++) {
            int row = m0 + wm * 32 + mb * 16 + kg * 4 + r;
#pragma unroll
            for (int nb = 0; nb < 2; nb++)
                Wx1[(size_t)row * HID + n0 + wn * 32 + nb * 16 + fr] = acc[mb][nb][r];
            float ve = acc[mb][0][r] * as0 + acc[mb][1][r] * as1;
            float vt = acc[mb][0][r] * at0 + acc[mb][1][r] * at1;
#pragma unroll
            for (int msk = 1; msk < 16; msk <<= 1) {
                ve += __shfl_xor(ve, msk, 64);
                vt += __shfl_xor(vt, msk, 64);
            }
            if (fr == 0) {
                esP[wm][wn][mb * 16 + kg * 4 + r] = ve;
                etP[wm][wn][mb * 16 + kg * 4 + r] = vt;
            }
        }
    }
    __syncthreads();
    if (t < 64) {
        int wmm = t >> 5, ri = t & 31;
        es[h * NND + m0 + t] = esP[wmm][0][ri] + esP[wmm][1][ri];
        et[h * NND + m0 + t] = etP[wmm][0][ri] + etP[wmm][1][ri];
    }
}

// ---------------- GEMM2 (MFMA split-bf16): Wx2 = h1(4096x256) @ W2(256x1024) ----------------
__global__ __launch_bounds__(256) void gemm2_k(
        const float* __restrict__ h1,
        const unsigned short* __restrict__ Wh, const unsigned short* __restrict__ Wl,
        float* __restrict__ Wx2) {
    __shared__ unsigned short Ah[64][LDA], Al[64][LDA], Bh[64][LDA], Bl[64][LDA];
    const int t = threadIdx.x, lane = t & 63, w = t >> 6;
    const int wm = w >> 1, wn = w & 1;
    const int n0 = blockIdx.x * 64, m0 = blockIdx.y * 64;
    const int fr = lane & 15, kg = lane >> 4;
    f32x4 z4 = {0.f, 0.f, 0.f, 0.f};
    f32x4 acc[2][2] = {{z4, z4}, {z4, z4}};
    for (int k0 = 0; k0 < HID; k0 += 32) {
#pragma unroll
        for (int q = 0; q < 2; q++) {
            int p = t + 256 * q, r = p >> 3, kq = (p & 7) * 4;
            float4 av = *(const float4*)&h1[(size_t)(m0 + r) * HID + k0 + kq];
            float fv[4] = {av.x, av.y, av.z, av.w};
            unsigned short hi[4], lo[4];
#pragma unroll
            for (int i = 0; i < 4; i++) { hi[i] = f2bf(fv[i]); lo[i] = f2bf(fv[i] - bf2f(hi[i])); }
            *(u16x4*)&Ah[r][kq] = (u16x4){hi[0], hi[1], hi[2], hi[3]};
            *(u16x4*)&Al[r][kq] = (u16x4){lo[0], lo[1], lo[2], lo[3]};
        }
        {
            int r = t >> 2, kq = (t & 3) * 8;
            *(u16x8*)&Bh[r][kq] = *(const u16x8*)&Wh[(size_t)(n0 + r) * HID + k0 + kq];
            *(u16x8*)&Bl[r][kq] = *(const u16x8*)&Wl[(size_t)(n0 + r) * HID + k0 + kq];
        }
        __syncthreads();
        bf16x8 ah0 = *(bf16x8*)&Ah[wm * 32 + fr][kg * 8];
        bf16x8 ah1 = *(bf16x8*)&Ah[wm * 32 + 16 + fr][kg * 8];
        bf16x8 al0 = *(bf16x8*)&Al[wm * 32 + fr][kg * 8];
        bf16x8 al1 = *(bf16x8*)&Al[wm * 32 + 16 + fr][kg * 8];
        bf16x8 bh0 = *(bf16x8*)&Bh[wn * 32 + fr][kg * 8];
        bf16x8 bh1 = *(bf16x8*)&Bh[wn * 32 + 16 + fr][kg * 8];
        bf16x8 bl0 = *(bf16x8*)&Bl[wn * 32 + fr][kg * 8];
        bf16x8 bl1 = *(bf16x8*)&Bl[wn * 32 + 16 + fr][kg * 8];
        MM(ah0, bh0, acc[0][0]); MM(ah0, bl0, acc[0][0]); MM(al0, bh0, acc[0][0]);
        MM(ah0, bh1, acc[0][1]); MM(ah0, bl1, acc[0][1]); MM(al0, bh1, acc[0][1]);
        MM(ah1, bh0, acc[1][0]); MM(ah1, bl0, acc[1][0]); MM(al1, bh0, acc[1][0]);
        MM(ah1, bh1, acc[1][1]); MM(ah1, bl1, acc[1][1]); MM(al1, bh1, acc[1][1]);
        __syncthreads();
    }
#pragma unroll
    for (int mb = 0; mb < 2; mb++)
#pragma unroll
        for (int r = 0; r < 4; r++) {
            int row = m0 + wm * 32 + mb * 16 + kg * 4 + r;
#pragma unroll
            for (int nb = 0; nb < 2; nb++)
                Wx2[(size_t)row * C2 + n0 + wn * 32 + nb * 16 + fr] = acc[mb][nb][r];
        }
}

// ---------------- per-node scores layer 2 ----------------
__global__ void escore2_k(const float* __restrict__ Wx2, const float* __restrict__ attn2,
                          float* __restrict__ es, float* __restrict__ et) {
    __shared__ float red[8];
    const int i = blockIdx.x;
    const int t = threadIdx.x;
    const int wid = t >> 6, lane = t & 63;
    for (int h = 0; h < HEADS; h++) {
        float v = Wx2[i * C2 + h * D2 + t];
        float ps = v * attn2[h * 2 * D2 + t];
        float pt = v * attn2[h * 2 * D2 + D2 + t];
        ps = wave_sum(ps);
        pt = wave_sum(pt);
        if (lane == 0) { red[wid] = ps; red[4 + wid] = pt; }
        __syncthreads();
        if (t == 0) {
            es[h * NND + i] = red[0] + red[1] + red[2] + red[3];
            et[h * NND + i] = red[4] + red[5] + red[6] + red[7];
        }
        __syncthreads();
    }
}

// ---------------- rank-based sort ----------------
__global__ void rank_sort_k(const float* __restrict__ et, float* __restrict__ ts,
                            int* __restrict__ perm) {
    __shared__ float key[NND];
    __shared__ int pr[64];
    const int h = blockIdx.y;
    const int e0 = blockIdx.x * 64;
    const int t = threadIdx.x;
    const int e = t & 63, sg = t >> 6;
    for (int p = t; p < NND; p += 256) key[p] = et[h * NND + p];
    if (t < 64) pr[t] = 0;
    __syncthreads();
    const int myIdx = e0 + e;
    const float myV = key[myIdx];
    int rank = 0;
    const int kbeg = sg * (NND / 4);
#pragma unroll 4
    for (int k = kbeg; k < kbeg + NND / 4; k++) {
        float v = key[k];
        rank += (v < myV || (v == myV && k < myIdx)) ? 1 : 0;
    }
    atomicAdd(&pr[e], rank);
    __syncthreads();
    if (t < 64) {
        int r = pr[t];
        ts[h * NND + r] = key[e0 + t];
        perm[h * NND + r] = e0 + t;
    }
}

// ---------------- layer-1 scan pass 1 (heads folded) ----------------
__global__ void scan1_p1_k(const float* __restrict__ V, const float* __restrict__ ts,
                           const int* __restrict__ perm,
                           float* __restrict__ cTA, float* __restrict__ cTB,
                           float* __restrict__ cSA, float* __restrict__ cSB) {
    const int ch = blockIdx.x;
    const int t = threadIdx.x;
    const int h = t >> 6, d = t & 63;
    const float tmax = ts[h * NND + NND - 1];
    float aA = 0.f, aB = 0.f, aSA = 0.f, aSB = 0.f;
    const int k0 = ch * CHR1;
    for (int r = 0; r < CHR1; r++) {
        int k = k0 + r;
        float u = ts[h * NND + k] - tmax;
        float wA = expf(u);
        float wB = expf(LEAKY * u);
        int j = perm[h * NND + k];
        float v = V[j * HID + h * D1 + d];
        aA += wA * v; aB += wB * v; aSA += wA; aSB += wB;
    }
    cTA[(h * CH1 + ch) * D1 + d] = aA;
    cTB[(h * CH1 + ch) * D1 + d] = aB;
    if (d == 0) { cSA[h * CH1 + ch] = aSA; cSB[h * CH1 + ch] = aSB; }
}

// ---------------- layer-2 scan pass 1 ----------------
__global__ void scan2_p1_k(const float* __restrict__ V, const float* __restrict__ ts,
                           const int* __restrict__ perm,
                           float* __restrict__ cTA, float* __restrict__ cTB,
                           float* __restrict__ cSA, float* __restrict__ cSB) {
    const int ch = blockIdx.x, h = blockIdx.y;
    const int d = threadIdx.x;
    const float tmax = ts[h * NND + NND - 1];
    float aA = 0.f, aB = 0.f, aSA = 0.f, aSB = 0.f;
    const int k0 = ch * CHR2;
    for (int r = 0; r < CHR2; r++) {
        int k = k0 + r;
        float u = ts[h * NND + k] - tmax;
        float wA = expf(u);
        float wB = expf(LEAKY * u);
        int j = perm[h * NND + k];
        float v = V[j * C2 + h * D2 + d];
        aA += wA * v; aB += wB * v; aSA += wA; aSB += wB;
    }
    cTA[(h * CH2 + ch) * D2 + d] = aA;
    cTB[(h * CH2 + ch) * D2 + d] = aB;
    if (d == 0) { cSA[h * CH2 + ch] = aSA; cSB[h * CH2 + ch] = aSB; }
}

// ---------------- layer-1 scan pass 3 (self-computed prefix; heads folded) ----------------
__global__ void scan1_p3_k(const float* __restrict__ V, const float* __restrict__ ts,
                           const int* __restrict__ perm,
                           const float* __restrict__ cTA, const float* __restrict__ cTB,
                           const float* __restrict__ cSA, const float* __restrict__ cSB,
                           float* __restrict__ A, float* __restrict__ B,
                           float* __restrict__ SA, float* __restrict__ SB) {
    const int ch = blockIdx.x;
    const int t = threadIdx.x;
    const int h = t >> 6, d = t & 63;
    const float tmax = ts[h * NND + NND - 1];
    float pre = 0.f, tot = 0.f, preB = 0.f, totB = 0.f;
    float runSA = 0.f, runSB = 0.f, totSA = 0.f, totSB = 0.f;
#pragma unroll 8
    for (int c = 0; c < CH1; c++) {
        float vA = cTA[(h * CH1 + c) * D1 + d];
        float vB = cTB[(h * CH1 + c) * D1 + d];
        float sA = cSA[h * CH1 + c];
        float sB = cSB[h * CH1 + c];
        tot += vA; totB += vB; totSA += sA; totSB += sB;
        if (c < ch) { pre += vA; preB += vB; runSA += sA; runSB += sB; }
    }
    float runA = pre, runB = preB;
    const float totA = tot;
    const int k0 = ch * CHR1;
    for (int r = 0; r < CHR1; r++) {
        int k = k0 + r;
        float u = ts[h * NND + k] - tmax;
        float wA = expf(u);
        float wB = expf(LEAKY * u);
        int j = perm[h * NND + k];
        float v = V[j * HID + h * D1 + d];
        size_t o = ((size_t)(h * NP1 + k)) * D1 + d;
        A[o] = totA - runA;
        B[o] = runB;
        if (d == 0) {
            SA[h * NP1 + k] = totSA - runSA;
            SB[h * NP1 + k] = runSB;
        }
        runA += wA * v; runB += wB * v; runSA += wA; runSB += wB;
    }
    if (ch == CH1 - 1) {
        size_t o = ((size_t)(h * NP1 + NND)) * D1 + d;
        A[o] = totA - runA;
        B[o] = runB;
        if (d == 0) {
            SA[h * NP1 + NND] = totSA - runSA;
            SB[h * NP1 + NND] = runSB;
        }
    }
}

// ---------------- layer-2 scan pass 3 (self-computed prefix) ----------------
__global__ void scan2_p3_k(const float* __restrict__ V, const float* __restrict__ ts,
                           const int* __restrict__ perm,
                           const float* __restrict__ cTA, const float* __restrict__ cTB,
                           const float* __restrict__ cSA, const float* __restrict__ cSB,
                           float* __restrict__ A, float* __restrict__ B,
                           float* __restrict__ SA, float* __restrict__ SB) {
    const int ch = blockIdx.x, h = blockIdx.y;
    const int d = threadIdx.x;
    const float tmax = ts[h * NND + NND - 1];
    float pre = 0.f, tot = 0.f, preB = 0.f, totB = 0.f;
    float runSA = 0.f, runSB = 0.f, totSA = 0.f, totSB = 0.f;
#pragma unroll 8
    for (int c = 0; c < CH2; c++) {
        float vA = cTA[(h * CH2 + c) * D2 + d];
        float vB = cTB[(h * CH2 + c) * D2 + d];
        float sA = cSA[h * CH2 + c];
        float sB = cSB[h * CH2 + c];
        tot += vA; totB += vB; totSA += sA; totSB += sB;
        if (c < ch) { pre += vA; preB += vB; runSA += sA; runSB += sB; }
    }
    float runA = pre, runB = preB;
    const float totA = tot;
    const int k0 = ch * CHR2;
    for (int r = 0; r < CHR2; r++) {
        int k = k0 + r;
        float u = ts[h * NND + k] - tmax;
        float wA = expf(u);
        float wB = expf(LEAKY * u);
        int j = perm[h * NND + k];
        float v = V[j * C2 + h * D2 + d];
        size_t o = ((size_t)(h * NP1 + k)) * D2 + d;
        A[o] = totA - runA;
        B[o] = runB;
        if (d == 0) {
            SA[h * NP1 + k] = totSA - runSA;
            SB[h * NP1 + k] = runSB;
        }
        runA += wA * v; runB += wB * v; runSA += wA; runSB += wB;
    }
    if (ch == CH2 - 1) {
        size_t o = ((size_t)(h * NP1 + NND)) * D2 + d;
        A[o] = totA - runA;
        B[o] = runB;
        if (d == 0) {
            SA[h * NP1 + NND] = totSA - runSA;
            SB[h * NP1 + NND] = runSB;
        }
    }
}

// ---------------- lookup layer 1: combine + ELU -> h1 ----------------
__global__ void lookup1_k(const float* __restrict__ es, const float* __restrict__ ts,
                          const float* __restrict__ A, const float* __restrict__ B,
                          const float* __restrict__ SA, const float* __restrict__ SB,
                          float* __restrict__ h1) {
    const int i = blockIdx.x;
    const int t = threadIdx.x;
    const int h = t >> 6, d = t & 63;
    float c = es[h * NND + i];
    float tmax = ts[h * NND + NND - 1];
    float s = c + tmax;
    float m = (s >= 0.f) ? s : LEAKY * s;
    float al = expf(s - m);
    float be = expf(LEAKY * s - m);
    int k = lower_bound_f(ts + h * NND, -c);
    size_t o = ((size_t)(h * NP1 + k)) * D1 + d;
    float num = al * A[o] + be * B[o];
    float den = al * SA[h * NP1 + k] + be * SB[h * NP1 + k];
    float val = num / den;
    h1[i * HID + t] = (val > 0.f) ? val : expm1f(val);
}

// ---------------- lookup layer 2: combine + head-mean + ELU + LayerNorm ----------------
__global__ void lookup2_k(const float* __restrict__ es, const float* __restrict__ ts,
                          const float* __restrict__ A, const float* __restrict__ B,
                          const float* __restrict__ SA, const float* __restrict__ SB,
                          const float* __restrict__ gamma, const float* __restrict__ betap,
                          float* __restrict__ out) {
    __shared__ float red[4];
    const int i = blockIdx.x;
    const int t = threadIdx.x;
    const int wid = t >> 6, lane = t & 63;
    float acc = 0.f;
    for (int h = 0; h < HEADS; h++) {
        float c = es[h * NND + i];
        float tmax = ts[h * NND + NND - 1];
        float s = c + tmax;
        float m = (s >= 0.f) ? s : LEAKY * s;
        float al = expf(s - m);
        float be = expf(LEAKY * s - m);
        int k = lower_bound_f(ts + h * NND, -c);
        size_t o = ((size_t)(h * NP1 + k)) * D2 + t;
        float num = al * A[o] + be * B[o];
        float den = al * SA[h * NP1 + k] + be * SB[h * NP1 + k];
        acc += num / den;
    }
    acc *= 0.25f;
    float xv = (acc > 0.f) ? acc : expm1f(acc);
    float sv = wave_sum(xv);
    if (lane == 0) red[wid] = sv;
    __syncthreads();
    float mu = (red[0] + red[1] + red[2] + red[3]) * (1.f / 256.f);
    __syncthreads();
    float dv = xv - mu;
    float s2 = wave_sum(dv * dv);
    if (lane == 0) red[wid] = s2;
    __syncthreads();
    float var = (red[0] + red[1] + red[2] + red[3]) * (1.f / 256.f);
    out[i * D2 + t] = gamma[t] * dv * rsqrtf(var + LN_EPS) + betap[t];
}

extern "C" void kernel_launch(void* const* d_in, const int* in_sizes, int n_in,
                              void* d_out, int out_size, void* d_ws, size_t ws_size,
                              hipStream_t stream) {
    const float* x     = (const float*)d_in[0];
    const float* W1    = (const float*)d_in[1];
    const float* attn1 = (const float*)d_in[2];
    const float* W2    = (const float*)d_in[3];
    const float* attn2 = (const float*)d_in[4];
    const float* gamma = (const float*)d_in[5];
    const float* betap = (const float*)d_in[6];
    float* out = (float*)d_out;

    char* ws = (char*)d_ws;
    size_t off = 0;
    auto alloc = [&](size_t nbytes) -> void* {
        void* p = (void*)(ws + off);
        off += (nbytes + 255) & ~(size_t)255;
        return p;
    };

    float* Wx1 = (float*)alloc((size_t)NND * HID * 4);
    float* Wx2 = (float*)alloc((size_t)NND * C2 * 4);
    float* h1  = (float*)alloc((size_t)NND * HID * 4);
    float* es1 = (float*)alloc((size_t)HEADS * NND * 4);
    float* et1 = (float*)alloc((size_t)HEADS * NND * 4);
    float* es2 = (float*)alloc((size_t)HEADS * NND * 4);
    float* et2 = (float*)alloc((size_t)HEADS * NND * 4);
    float* ts1 = (float*)alloc((size_t)HEADS * NND * 4);
    float* ts2 = (float*)alloc((size_t)HEADS * NND * 4);
    int* perm1 = (int*)alloc((size_t)HEADS * NND * 4);
    int* perm2 = (int*)alloc((size_t)HEADS * NND * 4);
    float* A   = (float*)alloc((size_t)HEADS * NP1 * D2 * 4);
    float* B   = (float*)alloc((size_t)HEADS * NP1 * D2 * 4);
    float* SA  = (float*)alloc((size_t)HEADS * NP1 * 4);
    float* SB  = (float*)alloc((size_t)HEADS * NP1 * 4);
    float* cTA = (float*)alloc((size_t)65536 * 4);
    float* cTB = (float*)alloc((size_t)65536 * 4);
    float* cSA = (float*)alloc((size_t)HEADS * CH1 * 4);
    float* cSB = (float*)alloc((size_t)HEADS * CH1 * 4);
    unsigned short* W1h = (unsigned short*)alloc((size_t)32768 * 2);
    unsigned short* W1l = (unsigned short*)alloc((size_t)32768 * 2);
    unsigned short* W2h = (unsigned short*)alloc((size_t)262144 * 2);
    unsigned short* W2l = (unsigned short*)alloc((size_t)262144 * 2);
    (void)ws_size; (void)in_sizes; (void)n_in; (void)out_size;

    dim3 gSort(NND / 64, HEADS);
    dim3 gScan2(CH2, HEADS);

    prep_w_k<<<1152, 256, 0, stream>>>(W1, W2, W1h, W1l, W2h, W2l);

    // ---- layer 1 ----
    gemm1_k<<<dim3(HID / 64, NND / 64), 256, 0, stream>>>(x, W1h, W1l, attn1, Wx1, es1, et1);
    rank_sort_k<<<gSort, 256, 0, stream>>>(et1, ts1, perm1);
    scan1_p1_k<<<CH1, 256, 0, stream>>>(Wx1, ts1, perm1, cTA, cTB, cSA, cSB);
    scan1_p3_k<<<CH1, 256, 0, stream>>>(Wx1, ts1, perm1, cTA, cTB, cSA, cSB, A, B, SA, SB);
    lookup1_k<<<NND, 256, 0, stream>>>(es1, ts1, A, B, SA, SB, h1);

    // ---- layer 2 ----
    gemm2_k<<<dim3(C2 / 64, NND / 64), 256, 0, stream>>>(h1, W2h, W2l, Wx2);
    escore2_k<<<NND, 256, 0, stream>>>(Wx2, attn2, es2, et2);
    rank_sort_k<<<gSort, 256, 0, stream>>>(et2, ts2, perm2);
    scan2_p1_k<<<gScan2, 256, 0, stream>>>(Wx2, ts2, perm2, cTA, cTB, cSA, cSB);
    scan2_p3_k<<<gScan2, 256, 0, stream>>>(Wx2, ts2, perm2, cTA, cTB, cSA, cSB, A, B, SA, SB);
    lookup2_k<<<NND, 256, 0, stream>>>(es2, ts2, A, B, SA, SB, gamma, betap, out);
}

// Round 4
// 223.597 us; speedup vs baseline: 1.7493x; 1.0393x over previous
//
#include <hip/hip_runtime.h>
#include <math.h>

#define NND 4096
#define SDIM 128
#define HEADS 4
#define D1 64
#define HID 256
#define D2 256
#define C2 1024
#define NP1 (NND + 1)
#define CH1 128
#define CHR1 32
#define CH2 128
#define CHR2 32
#define LEAKY 0.2f
#define LN_EPS 1e-5f
#define LDA 40

typedef __attribute__((ext_vector_type(8))) short bf16x8;
typedef __attribute__((ext_vector_type(4))) float f32x4;
typedef __attribute__((ext_vector_type(8))) unsigned short u16x8;
typedef __attribute__((ext_vector_type(4))) unsigned short u16x4;

__device__ __forceinline__ unsigned short f2bf(float f) {
    union { float f; unsigned u; } v; v.f = f;
    unsigned r = v.u + 0x7FFFu + ((v.u >> 16) & 1u);
    return (unsigned short)(r >> 16);
}
__device__ __forceinline__ float bf2f(unsigned short s) {
    union { unsigned u; float f; } v; v.u = ((unsigned)s) << 16; return v.f;
}

__device__ __forceinline__ float wave_sum(float v) {
#pragma unroll
    for (int o = 32; o > 0; o >>= 1) v += __shfl_xor(v, o, 64);
    return v;
}

__device__ __forceinline__ int lower_bound_f(const float* __restrict__ a, float x) {
    int lo = 0, hi = NND;
    while (lo < hi) {
        int mid = (lo + hi) >> 1;
        if (a[mid] < x) lo = mid + 1; else hi = mid;
    }
    return lo;
}

// ---------------- prep: W1,W2 -> bf16 hi/lo [n][k]; fold attn2 through W2 ----------------
__global__ void prep_w_k(const float* __restrict__ W1, const float* __restrict__ W2,
                         const float* __restrict__ attn2,
                         unsigned short* __restrict__ W1h, unsigned short* __restrict__ W1l,
                         unsigned short* __restrict__ W2h, unsigned short* __restrict__ W2l,
                         float* __restrict__ w_es, float* __restrict__ w_et) {
    const int bid = blockIdx.x, t = threadIdx.x;
    if (bid < 128) {
        int id = bid * 256 + t;          // < 32768
        int n = id >> 7, k = id & 127;
        float v = W1[k * HID + n];
        unsigned short hi = f2bf(v);
        W1h[id] = hi; W1l[id] = f2bf(v - bf2f(hi));
    } else if (bid < 1152) {
        int j = (bid - 128) * 256 + t;   // < 262144
        int n = j >> 8, k = j & 255;
        float v = W2[k * C2 + n];
        unsigned short hi = f2bf(v);
        W2h[j] = hi; W2l[j] = f2bf(v - bf2f(hi));
    } else {
        // w_es[h][k] = sum_n W2[k][h*256+n]*attn2[h][n]; w_et uses attn2[h][256+n]
        int q = bid - 1152;              // 0..511
        int wid = t >> 6, lane = t & 63;
        int g = q * 4 + wid;             // 0..2047
        int k = g & 255;
        int hs = g >> 8;                 // 0..7
        int h = hs >> 1, sel = hs & 1;
        float acc = 0.f;
#pragma unroll
        for (int qq = 0; qq < 4; qq++)
            acc += W2[(size_t)k * C2 + h * 256 + qq * 64 + lane] *
                   attn2[h * 512 + sel * 256 + qq * 64 + lane];
        acc = wave_sum(acc);
        if (lane == 0) {
            if (sel) w_et[h * 256 + k] = acc;
            else     w_es[h * 256 + k] = acc;
        }
    }
}

#define MM(a, b, c) c = __builtin_amdgcn_mfma_f32_16x16x32_bf16(a, b, c, 0, 0, 0)

// ---------------- GEMM1 (MFMA split-bf16) + fused escore1 ----------------
__global__ __launch_bounds__(256) void gemm1_k(
        const float* __restrict__ x,
        const unsigned short* __restrict__ Wh, const unsigned short* __restrict__ Wl,
        const float* __restrict__ attn1,
        float* __restrict__ Wx1, float* __restrict__ es, float* __restrict__ et) {
    __shared__ unsigned short Ah[64][LDA], Al[64][LDA], Bh[64][LDA], Bl[64][LDA];
    __shared__ float esP[2][2][32], etP[2][2][32];
    const int t = threadIdx.x, lane = t & 63, w = t >> 6;
    const int wm = w >> 1, wn = w & 1;
    const int h = blockIdx.x, n0 = h * 64, m0 = blockIdx.y * 64;
    const int fr = lane & 15, kg = lane >> 4;
    f32x4 z4 = {0.f, 0.f, 0.f, 0.f};
    f32x4 acc[2][2] = {{z4, z4}, {z4, z4}};
    for (int k0 = 0; k0 < SDIM; k0 += 32) {
#pragma unroll
        for (int q = 0; q < 2; q++) {
            int p = t + 256 * q, r = p >> 3, kq = (p & 7) * 4;
            float4 av = *(const float4*)&x[(size_t)(m0 + r) * SDIM + k0 + kq];
            float fv[4] = {av.x, av.y, av.z, av.w};
            unsigned short hi[4], lo[4];
#pragma unroll
            for (int i = 0; i < 4; i++) { hi[i] = f2bf(fv[i]); lo[i] = f2bf(fv[i] - bf2f(hi[i])); }
            *(u16x4*)&Ah[r][kq] = (u16x4){hi[0], hi[1], hi[2], hi[3]};
            *(u16x4*)&Al[r][kq] = (u16x4){lo[0], lo[1], lo[2], lo[3]};
        }
        {
            int r = t >> 2, kq = (t & 3) * 8;
            *(u16x8*)&Bh[r][kq] = *(const u16x8*)&Wh[(size_t)(n0 + r) * SDIM + k0 + kq];
            *(u16x8*)&Bl[r][kq] = *(const u16x8*)&Wl[(size_t)(n0 + r) * SDIM + k0 + kq];
        }
        __syncthreads();
        bf16x8 ah0 = *(bf16x8*)&Ah[wm * 32 + fr][kg * 8];
        bf16x8 ah1 = *(bf16x8*)&Ah[wm * 32 + 16 + fr][kg * 8];
        bf16x8 al0 = *(bf16x8*)&Al[wm * 32 + fr][kg * 8];
        bf16x8 al1 = *(bf16x8*)&Al[wm * 32 + 16 + fr][kg * 8];
        bf16x8 bh0 = *(bf16x8*)&Bh[wn * 32 + fr][kg * 8];
        bf16x8 bh1 = *(bf16x8*)&Bh[wn * 32 + 16 + fr][kg * 8];
        bf16x8 bl0 = *(bf16x8*)&Bl[wn * 32 + fr][kg * 8];
        bf16x8 bl1 = *(bf16x8*)&Bl[wn * 32 + 16 + fr][kg * 8];
        MM(ah0, bh0, acc[0][0]); MM(ah0, bl0, acc[0][0]); MM(al0, bh0, acc[0][0]);
        MM(ah0, bh1, acc[0][1]); MM(ah0, bl1, acc[0][1]); MM(al0, bh1, acc[0][1]);
        MM(ah1, bh0, acc[1][0]); MM(ah1, bl0, acc[1][0]); MM(al1, bh0, acc[1][0]);
        MM(ah1, bh1, acc[1][1]); MM(ah1, bl1, acc[1][1]); MM(al1, bh1, acc[1][1]);
        __syncthreads();
    }
    const float as0 = attn1[h * 128 + wn * 32 + fr];
    const float as1 = attn1[h * 128 + wn * 32 + 16 + fr];
    const float at0 = attn1[h * 128 + 64 + wn * 32 + fr];
    const float at1 = attn1[h * 128 + 64 + wn * 32 + 16 + fr];
#pragma unroll
    for (int mb = 0; mb < 2; mb++) {
#pragma unroll
        for (int r = 0; r < 4; r++) {
            int row = m0 + wm * 32 + mb * 16 + kg * 4 + r;
#pragma unroll
            for (int nb = 0; nb < 2; nb++)
                Wx1[(size_t)row * HID + n0 + wn * 32 + nb * 16 + fr] = acc[mb][nb][r];
            float ve = acc[mb][0][r] * as0 + acc[mb][1][r] * as1;
            float vt = acc[mb][0][r] * at0 + acc[mb][1][r] * at1;
#pragma unroll
            for (int msk = 1; msk < 16; msk <<= 1) {
                ve += __shfl_xor(ve, msk, 64);
                vt += __shfl_xor(vt, msk, 64);
            }
            if (fr == 0) {
                esP[wm][wn][mb * 16 + kg * 4 + r] = ve;
                etP[wm][wn][mb * 16 + kg * 4 + r] = vt;
            }
        }
    }
    __syncthreads();
    if (t < 64) {
        int wmm = t >> 5, ri = t & 31;
        es[h * NND + m0 + t] = esP[wmm][0][ri] + esP[wmm][1][ri];
        et[h * NND + m0 + t] = etP[wmm][0][ri] + etP[wmm][1][ri];
    }
}

// ---------------- GEMM2 (MFMA split-bf16) ----------------
__global__ __launch_bounds__(256) void gemm2_k(
        const float* __restrict__ h1,
        const unsigned short* __restrict__ Wh, const unsigned short* __restrict__ Wl,
        float* __restrict__ Wx2) {
    __shared__ unsigned short Ah[64][LDA], Al[64][LDA], Bh[64][LDA], Bl[64][LDA];
    const int t = threadIdx.x, lane = t & 63, w = t >> 6;
    const int wm = w >> 1, wn = w & 1;
    const int n0 = blockIdx.x * 64, m0 = blockIdx.y * 64;
    const int fr = lane & 15, kg = lane >> 4;
    f32x4 z4 = {0.f, 0.f, 0.f, 0.f};
    f32x4 acc[2][2] = {{z4, z4}, {z4, z4}};
    for (int k0 = 0; k0 < HID; k0 += 32) {
#pragma unroll
        for (int q = 0; q < 2; q++) {
            int p = t + 256 * q, r = p >> 3, kq = (p & 7) * 4;
            float4 av = *(const float4*)&h1[(size_t)(m0 + r) * HID + k0 + kq];
            float fv[4] = {av.x, av.y, av.z, av.w};
            unsigned short hi[4], lo[4];
#pragma unroll
            for (int i = 0; i < 4; i++) { hi[i] = f2bf(fv[i]); lo[i] = f2bf(fv[i] - bf2f(hi[i])); }
            *(u16x4*)&Ah[r][kq] = (u16x4){hi[0], hi[1], hi[2], hi[3]};
            *(u16x4*)&Al[r][kq] = (u16x4){lo[0], lo[1], lo[2], lo[3]};
        }
        {
            int r = t >> 2, kq = (t & 3) * 8;
            *(u16x8*)&Bh[r][kq] = *(const u16x8*)&Wh[(size_t)(n0 + r) * HID + k0 + kq];
            *(u16x8*)&Bl[r][kq] = *(const u16x8*)&Wl[(size_t)(n0 + r) * HID + k0 + kq];
        }
        __syncthreads();
        bf16x8 ah0 = *(bf16x8*)&Ah[wm * 32 + fr][kg * 8];
        bf16x8 ah1 = *(bf16x8*)&Ah[wm * 32 + 16 + fr][kg * 8];
        bf16x8 al0 = *(bf16x8*)&Al[wm * 32 + fr][kg * 8];
        bf16x8 al1 = *(bf16x8*)&Al[wm * 32 + 16 + fr][kg * 8];
        bf16x8 bh0 = *(bf16x8*)&Bh[wn * 32 + fr][kg * 8];
        bf16x8 bh1 = *(bf16x8*)&Bh[wn * 32 + 16 + fr][kg * 8];
        bf16x8 bl0 = *(bf16x8*)&Bl[wn * 32 + fr][kg * 8];
        bf16x8 bl1 = *(bf16x8*)&Bl[wn * 32 + 16 + fr][kg * 8];
        MM(ah0, bh0, acc[0][0]); MM(ah0, bl0, acc[0][0]); MM(al0, bh0, acc[0][0]);
        MM(ah0, bh1, acc[0][1]); MM(ah0, bl1, acc[0][1]); MM(al0, bh1, acc[0][1]);
        MM(ah1, bh0, acc[1][0]); MM(ah1, bl0, acc[1][0]); MM(al1, bh0, acc[1][0]);
        MM(ah1, bh1, acc[1][1]); MM(ah1, bl1, acc[1][1]); MM(al1, bh1, acc[1][1]);
        __syncthreads();
    }
#pragma unroll
    for (int mb = 0; mb < 2; mb++)
#pragma unroll
        for (int r = 0; r < 4; r++) {
            int row = m0 + wm * 32 + mb * 16 + kg * 4 + r;
#pragma unroll
            for (int nb = 0; nb < 2; nb++)
                Wx2[(size_t)row * C2 + n0 + wn * 32 + nb * 16 + fr] = acc[mb][nb][r];
        }
}

// ---------------- rank-based sort ----------------
__global__ void rank_sort_k(const float* __restrict__ et, float* __restrict__ ts,
                            int* __restrict__ perm) {
    __shared__ float key[NND];
    __shared__ int pr[64];
    const int h = blockIdx.y;
    const int e0 = blockIdx.x * 64;
    const int t = threadIdx.x;
    const int e = t & 63, sg = t >> 6;
    for (int p = t; p < NND; p += 256) key[p] = et[h * NND + p];
    if (t < 64) pr[t] = 0;
    __syncthreads();
    const int myIdx = e0 + e;
    const float myV = key[myIdx];
    int rank = 0;
    const int kbeg = sg * (NND / 4);
#pragma unroll 4
    for (int k = kbeg; k < kbeg + NND / 4; k++) {
        float v = key[k];
        rank += (v < myV || (v == myV && k < myIdx)) ? 1 : 0;
    }
    atomicAdd(&pr[e], rank);
    __syncthreads();
    if (t < 64) {
        int r = pr[t];
        ts[h * NND + r] = key[e0 + t];
        perm[h * NND + r] = e0 + t;
    }
}

// ---------------- weight precompute + scalar scan (block per head) ----------------
__global__ __launch_bounds__(1024) void wprep_k(const float* __restrict__ ts,
                                                float* __restrict__ wA, float* __restrict__ wB,
                                                float* __restrict__ SA, float* __restrict__ SB) {
    __shared__ float sA_lds[16], sB_lds[16];
    const int h = blockIdx.x, t = threadIdx.x;
    const int lane = t & 63, w = t >> 6;
    const float tmax = ts[h * NND + NND - 1];
    float a[4], b[4];
    float la = 0.f, lb = 0.f;
#pragma unroll
    for (int q = 0; q < 4; q++) {
        float u = ts[h * NND + t * 4 + q] - tmax;
        a[q] = expf(u); b[q] = expf(LEAKY * u);
        la += a[q]; lb += b[q];
        wA[h * NND + t * 4 + q] = a[q];
        wB[h * NND + t * 4 + q] = b[q];
    }
    float sa = la, sb = lb;
#pragma unroll
    for (int o = 1; o < 64; o <<= 1) {
        float ua = __shfl_up(sa, o, 64);
        float ub = __shfl_up(sb, o, 64);
        if (lane >= o) { sa += ua; sb += ub; }
    }
    if (lane == 63) { sA_lds[w] = sa; sB_lds[w] = sb; }
    __syncthreads();
    float baseA = 0.f, baseB = 0.f, totA = 0.f, totB = 0.f;
#pragma unroll
    for (int ww = 0; ww < 16; ww++) {
        float va = sA_lds[ww], vb = sB_lds[ww];
        totA += va; totB += vb;
        if (ww < w) { baseA += va; baseB += vb; }
    }
    float preA = baseA + sa - la;   // exclusive prefix at this thread's first elem
    float preB = baseB + sb - lb;
#pragma unroll
    for (int q = 0; q < 4; q++) {
        SA[h * NP1 + t * 4 + q] = totA - preA;   // suffix incl k
        SB[h * NP1 + t * 4 + q] = preB;          // prefix excl k
        preA += a[q]; preB += b[q];
    }
    if (t == 1023) { SA[h * NP1 + NND] = 0.f; SB[h * NP1 + NND] = totB; }
}

// ---------------- layer-1 scan pass 1 (heads folded, unrolled) ----------------
__global__ __launch_bounds__(256) void scan1_p1_k(const float* __restrict__ V,
        const int* __restrict__ perm, const float* __restrict__ wA, const float* __restrict__ wB,
        float* __restrict__ cTA, float* __restrict__ cTB) {
    const int ch = blockIdx.x, t = threadIdx.x;
    const int h = t >> 6, d = t & 63;
    const int k0 = ch * CHR1;
    float aA = 0.f, aB = 0.f;
#pragma unroll
    for (int r = 0; r < CHR1; r++) {
        int k = k0 + r;
        int j = perm[h * NND + k];
        float wa = wA[h * NND + k], wb = wB[h * NND + k];
        float v = V[(size_t)j * HID + h * D1 + d];
        aA += wa * v; aB += wb * v;
    }
    cTA[(h * CH1 + ch) * D1 + d] = aA;
    cTB[(h * CH1 + ch) * D1 + d] = aB;
}

// ---------------- layer-2 scan pass 1 ----------------
__global__ __launch_bounds__(256) void scan2_p1_k(const float* __restrict__ V,
        const int* __restrict__ perm, const float* __restrict__ wA, const float* __restrict__ wB,
        float* __restrict__ cTA, float* __restrict__ cTB) {
    const int ch = blockIdx.x, h = blockIdx.y;
    const int d = threadIdx.x;
    const int k0 = ch * CHR2;
    float aA = 0.f, aB = 0.f;
#pragma unroll
    for (int r = 0; r < CHR2; r++) {
        int k = k0 + r;
        int j = perm[h * NND + k];
        float wa = wA[h * NND + k], wb = wB[h * NND + k];
        float v = V[(size_t)j * C2 + h * D2 + d];
        aA += wa * v; aB += wb * v;
    }
    cTA[(h * CH2 + ch) * D2 + d] = aA;
    cTB[(h * CH2 + ch) * D2 + d] = aB;
}

// ---------------- layer-1 scan pass 3 (register-staged) ----------------
__global__ __launch_bounds__(256) void scan1_p3_k(const float* __restrict__ V,
        const int* __restrict__ perm, const float* __restrict__ wA, const float* __restrict__ wB,
        const float* __restrict__ cTA, const float* __restrict__ cTB,
        float* __restrict__ A, float* __restrict__ B) {
    const int ch = blockIdx.x, t = threadIdx.x;
    const int h = t >> 6, d = t & 63;
    float runA = 0.f, runB = 0.f, totA = 0.f, totB = 0.f;
#pragma unroll 8
    for (int c = 0; c < CH1; c++) {
        float vA = cTA[(h * CH1 + c) * D1 + d];
        float vB = cTB[(h * CH1 + c) * D1 + d];
        totA += vA; totB += vB;
        if (c < ch) { runA += vA; runB += vB; }
    }
    const int k0 = ch * CHR1;
    float v[CHR1], wa[CHR1], wb[CHR1];
#pragma unroll
    for (int r = 0; r < CHR1; r++) {
        int k = k0 + r;
        int j = perm[h * NND + k];
        wa[r] = wA[h * NND + k];
        wb[r] = wB[h * NND + k];
        v[r] = V[(size_t)j * HID + h * D1 + d];
    }
#pragma unroll
    for (int r = 0; r < CHR1; r++) {
        size_t o = ((size_t)(h * NP1 + k0 + r)) * D1 + d;
        A[o] = totA - runA;
        B[o] = runB;
        runA += wa[r] * v[r];
        runB += wb[r] * v[r];
    }
    if (ch == CH1 - 1) {
        size_t o = ((size_t)(h * NP1 + NND)) * D1 + d;
        A[o] = totA - runA;
        B[o] = runB;
    }
}

// ---------------- layer-2 scan pass 3 (register-staged) ----------------
__global__ __launch_bounds__(256) void scan2_p3_k(const float* __restrict__ V,
        const int* __restrict__ perm, const float* __restrict__ wA, const float* __restrict__ wB,
        const float* __restrict__ cTA, const float* __restrict__ cTB,
        float* __restrict__ A, float* __restrict__ B) {
    const int ch = blockIdx.x, h = blockIdx.y;
    const int d = threadIdx.x;
    float runA = 0.f, runB = 0.f, totA = 0.f, totB = 0.f;
#pragma unroll 8
    for (int c = 0; c < CH2; c++) {
        float vA = cTA[(h * CH2 + c) * D2 + d];
        float vB = cTB[(h * CH2 + c) * D2 + d];
        totA += vA; totB += vB;
        if (c < ch) { runA += vA; runB += vB; }
    }
    const int k0 = ch * CHR2;
    float v[CHR2], wa[CHR2], wb[CHR2];
#pragma unroll
    for (int r = 0; r < CHR2; r++) {
        int k = k0 + r;
        int j = perm[h * NND + k];
        wa[r] = wA[h * NND + k];
        wb[r] = wB[h * NND + k];
        v[r] = V[(size_t)j * C2 + h * D2 + d];
    }
#pragma unroll
    for (int r = 0; r < CHR2; r++) {
        size_t o = ((size_t)(h * NP1 + k0 + r)) * D2 + d;
        A[o] = totA - runA;
        B[o] = runB;
        runA += wa[r] * v[r];
        runB += wb[r] * v[r];
    }
    if (ch == CH2 - 1) {
        size_t o = ((size_t)(h * NP1 + NND)) * D2 + d;
        A[o] = totA - runA;
        B[o] = runB;
    }
}

// ---------------- lookup layer 1: combine + ELU -> h1 (+ fused escore2) ----------------
__global__ __launch_bounds__(256) void lookup1_k(const float* __restrict__ es,
        const float* __restrict__ ts,
        const float* __restrict__ A, const float* __restrict__ Bv,
        const float* __restrict__ SA, const float* __restrict__ SB,
        const float* __restrict__ w_es, const float* __restrict__ w_et,
        float* __restrict__ h1, float* __restrict__ es2, float* __restrict__ et2) {
    __shared__ float red2[4][8];
    const int i = blockIdx.x, t = threadIdx.x;
    const int h = t >> 6, d = t & 63;
    const int lane = t & 63, wid = t >> 6;
    float c = es[h * NND + i];
    float tmax = ts[h * NND + NND - 1];
    float s = c + tmax;
    float m = (s >= 0.f) ? s : LEAKY * s;
    float al = expf(s - m);
    float be = expf(LEAKY * s - m);
    int k = lower_bound_f(ts + h * NND, -c);
    size_t o = ((size_t)(h * NP1 + k)) * D1 + d;
    float num = al * A[o] + be * Bv[o];
    float den = al * SA[h * NP1 + k] + be * SB[h * NP1 + k];
    float val = num / den;
    float hv = (val > 0.f) ? val : expm1f(val);
    h1[i * HID + t] = hv;
    // fused escore2: 8 dot products of the h1 row with folded W2*attn2 vectors
#pragma unroll
    for (int oo = 0; oo < 8; oo++) {
        int hh = oo >> 1;
        const float* wv = (oo & 1) ? w_et : w_es;
        float p = hv * wv[hh * HID + t];
        p = wave_sum(p);
        if (lane == 0) red2[wid][oo] = p;
    }
    __syncthreads();
    if (t < 8) {
        float sv = red2[0][t] + red2[1][t] + red2[2][t] + red2[3][t];
        int hh = t >> 1;
        if (t & 1) et2[hh * NND + i] = sv;
        else       es2[hh * NND + i] = sv;
    }
}

// ---------------- lookup layer 2: combine + head-mean + ELU + LayerNorm ----------------
__global__ __launch_bounds__(256) void lookup2_k(const float* __restrict__ es,
        const float* __restrict__ ts,
        const float* __restrict__ A, const float* __restrict__ B,
        const float* __restrict__ SA, const float* __restrict__ SB,
        const float* __restrict__ gamma, const float* __restrict__ betap,
        float* __restrict__ out) {
    __shared__ float red[4];
    const int i = blockIdx.x;
    const int t = threadIdx.x;
    const int wid = t >> 6, lane = t & 63;
    float acc = 0.f;
#pragma unroll
    for (int h = 0; h < HEADS; h++) {
        float c = es[h * NND + i];
        float tmax = ts[h * NND + NND - 1];
        float s = c + tmax;
        float m = (s >= 0.f) ? s : LEAKY * s;
        float al = expf(s - m);
        float be = expf(LEAKY * s - m);
        int k = lower_bound_f(ts + h * NND, -c);
        size_t o = ((size_t)(h * NP1 + k)) * D2 + t;
        float num = al * A[o] + be * B[o];
        float den = al * SA[h * NP1 + k] + be * SB[h * NP1 + k];
        acc += num / den;
    }
    acc *= 0.25f;
    float xv = (acc > 0.f) ? acc : expm1f(acc);
    float sv = wave_sum(xv);
    if (lane == 0) red[wid] = sv;
    __syncthreads();
    float mu = (red[0] + red[1] + red[2] + red[3]) * (1.f / 256.f);
    __syncthreads();
    float dv = xv - mu;
    float s2 = wave_sum(dv * dv);
    if (lane == 0) red[wid] = s2;
    __syncthreads();
    float var = (red[0] + red[1] + red[2] + red[3]) * (1.f / 256.f);
    out[i * D2 + t] = gamma[t] * dv * rsqrtf(var + LN_EPS) + betap[t];
}

extern "C" void kernel_launch(void* const* d_in, const int* in_sizes, int n_in,
                              void* d_out, int out_size, void* d_ws, size_t ws_size,
                              hipStream_t stream) {
    const float* x     = (const float*)d_in[0];
    const float* W1    = (const float*)d_in[1];
    const float* attn1 = (const float*)d_in[2];
    const float* W2    = (const float*)d_in[3];
    const float* attn2 = (const float*)d_in[4];
    const float* gamma = (const float*)d_in[5];
    const float* betap = (const float*)d_in[6];
    float* out = (float*)d_out;

    char* ws = (char*)d_ws;
    size_t off = 0;
    auto alloc = [&](size_t nbytes) -> void* {
        void* p = (void*)(ws + off);
        off += (nbytes + 255) & ~(size_t)255;
        return p;
    };

    float* Wx1 = (float*)alloc((size_t)NND * HID * 4);
    float* Wx2 = (float*)alloc((size_t)NND * C2 * 4);
    float* h1  = (float*)alloc((size_t)NND * HID * 4);
    float* es1 = (float*)alloc((size_t)HEADS * NND * 4);
    float* et1 = (float*)alloc((size_t)HEADS * NND * 4);
    float* es2 = (float*)alloc((size_t)HEADS * NND * 4);
    float* et2 = (float*)alloc((size_t)HEADS * NND * 4);
    float* ts1 = (float*)alloc((size_t)HEADS * NND * 4);
    float* ts2 = (float*)alloc((size_t)HEADS * NND * 4);
    int* perm1 = (int*)alloc((size_t)HEADS * NND * 4);
    int* perm2 = (int*)alloc((size_t)HEADS * NND * 4);
    float* A   = (float*)alloc((size_t)HEADS * NP1 * D2 * 4);
    float* B   = (float*)alloc((size_t)HEADS * NP1 * D2 * 4);
    float* SA  = (float*)alloc((size_t)HEADS * NP1 * 4);
    float* SB  = (float*)alloc((size_t)HEADS * NP1 * 4);
    float* cTA = (float*)alloc((size_t)131072 * 4);
    float* cTB = (float*)alloc((size_t)131072 * 4);
    float* wWA = (float*)alloc((size_t)HEADS * NND * 4);
    float* wWB = (float*)alloc((size_t)HEADS * NND * 4);
    unsigned short* W1h = (unsigned short*)alloc((size_t)32768 * 2);
    unsigned short* W1l = (unsigned short*)alloc((size_t)32768 * 2);
    unsigned short* W2h = (unsigned short*)alloc((size_t)262144 * 2);
    unsigned short* W2l = (unsigned short*)alloc((size_t)262144 * 2);
    float* w_es = (float*)alloc((size_t)HEADS * HID * 4);
    float* w_et = (float*)alloc((size_t)HEADS * HID * 4);
    (void)ws_size; (void)in_sizes; (void)n_in; (void)out_size;

    dim3 gSort(NND / 64, HEADS);

    prep_w_k<<<1664, 256, 0, stream>>>(W1, W2, attn2, W1h, W1l, W2h, W2l, w_es, w_et);

    // ---- layer 1 ----
    gemm1_k<<<dim3(HID / 64, NND / 64), 256, 0, stream>>>(x, W1h, W1l, attn1, Wx1, es1, et1);
    rank_sort_k<<<gSort, 256, 0, stream>>>(et1, ts1, perm1);
    wprep_k<<<HEADS, 1024, 0, stream>>>(ts1, wWA, wWB, SA, SB);
    scan1_p1_k<<<CH1, 256, 0, stream>>>(Wx1, perm1, wWA, wWB, cTA, cTB);
    scan1_p3_k<<<CH1, 256, 0, stream>>>(Wx1, perm1, wWA, wWB, cTA, cTB, A, B);
    lookup1_k<<<NND, 256, 0, stream>>>(es1, ts1, A, B, SA, SB, w_es, w_et, h1, es2, et2);

    // ---- layer 2 ----
    gemm2_k<<<dim3(C2 / 64, NND / 64), 256, 0, stream>>>(h1, W2h, W2l, Wx2);
    rank_sort_k<<<gSort, 256, 0, stream>>>(et2, ts2, perm2);
    wprep_k<<<HEADS, 1024, 0, stream>>>(ts2, wWA, wWB, SA, SB);
    scan2_p1_k<<<dim3(CH2, HEADS), 256, 0, stream>>>(Wx2, perm2, wWA, wWB, cTA, cTB);
    scan2_p3_k<<<dim3(CH2, HEADS), 256, 0, stream>>>(Wx2, perm2, wWA, wWB, cTA, cTB, A, B);
    lookup2_k<<<NND, 256, 0, stream>>>(es2, ts2, A, B, SA, SB, gamma, betap, out);
}